// Round 4
// baseline (544.882 us; speedup 1.0000x reference)
//
#include <hip/hip_runtime.h>
#include <hip/hip_bf16.h>

// R4: both GEMMs were vmcnt-serialized (k_conv MfmaUtil 6.8%, VGPR=64 ->
// compiler reused load regs, waits after every 1-2 loads). Fix: m97 pattern —
// width-4 global_load_lds staging (no VGPR round trip, one drain per tile)
// into +8-padded LDS rows (bank-conflict-free ds_read_b128). k_conv becomes a
// per-h Toeplitz GEMM (128bn x 128t per block, B rows = aligned sliding
// windows of the 8-copy Krev via per-row copy-select r=(-L)&7). k_glu stages
// its Y-tile the same way and runs 59 t-chunks for occupancy.

#define B_  16
#define T_  354
#define N_  64
#define H_  128
#define NS_ 32
#define BN_ (B_*N_)          // 1024 sequences
#define M_  (T_*BN_)         // 362496 positions (q = t*BN + bn)
#define TP_ 384              // padded tau range for xbf rows
#define KW_ 512              // padded Krev row length
#define TC_ 6                // t-chunk per k_glu block (59 chunks)

typedef __attribute__((ext_vector_type(8))) short bf16x8;
typedef __attribute__((ext_vector_type(4))) float f32x4;

static __device__ __forceinline__ unsigned short f32_to_bf16(float f) {
    unsigned int u = __float_as_uint(f);
    unsigned int r = 0x7FFFu + ((u >> 16) & 1u);   // RNE
    return (unsigned short)((u + r) >> 16);
}

// async global->LDS, 4 B per lane: stages one 256 B row per instruction with a
// wave-uniform LDS base (so padded LDS rows are legal, unlike width-16).
static __device__ __forceinline__ void gload_lds4(const void* g, void* l) {
    __builtin_amdgcn_global_load_lds(
        (const __attribute__((address_space(1))) unsigned int*)g,
        (__attribute__((address_space(3))) unsigned int*)l, 4, 0, 0);
}

// ---------------------------------------------------------------------------
// K0: fused prep — xbf[bn][tau] bf16 transpose-cast + W_out bf16 cast
// ---------------------------------------------------------------------------
__global__ void k_prep(const float* __restrict__ x, const float* __restrict__ W_out,
                       unsigned short* __restrict__ xbf, unsigned short* __restrict__ Wbf) {
    int id = blockIdx.x * blockDim.x + threadIdx.x;
    if (id < T_ * BN_) {
        int t  = id >> 10;
        int bn = id & 1023;
        float v = x[(bn >> 6) * (T_ * N_) + t * N_ + (bn & 63)];
        xbf[bn * TP_ + t] = f32_to_bf16(v);
    } else {
        int i = id - T_ * BN_;
        if (i < 2 * H_ * H_) Wbf[i] = f32_to_bf16(W_out[i]);
    }
}

// ---------------------------------------------------------------------------
// K1: S4D kernel taps (unchanged from R3).
//   K'[h,l] = 2*Sum_m Re(Cd[h,m] * exp(dtA*l))  (+ D[h] at l=0)
//   Krev_r[h][(353-l)+r] = bf16(K') for r=0..7  (shift-aligned reversed copies)
//   koff[t][h] = b_in[h] * cumsum_{l<=t} K'[h,l]
// ---------------------------------------------------------------------------
__global__ __launch_bounds__(512) void k_kern(
        const float* __restrict__ log_dt,
        const float* __restrict__ A_re, const float* __restrict__ A_im,
        const float* __restrict__ C_re, const float* __restrict__ C_im,
        const float* __restrict__ b_in, const float* __restrict__ D,
        unsigned short* __restrict__ Krev, float* __restrict__ koff) {
    const int h = blockIdx.x;
    const int l = threadIdx.x;

    float val = 0.0f;
    if (l < T_) {
        float dt = expf(log_dt[h]);
        float fl = (float)l;
#pragma unroll 4
        for (int m = 0; m < NS_; m++) {
            float are = A_re[h * NS_ + m], aim = A_im[h * NS_ + m];
            float dre = are * dt, dim = aim * dt;
            float er  = expf(dre);
            float c1, s1; __sincosf(dim, &s1, &c1);
            float e_re = er * c1, e_im = er * s1;
            float m_re = e_re - 1.0f, m_im = e_im;
            float inv  = 1.0f / (are * are + aim * aim);
            float q_re = (m_re * are + m_im * aim) * inv;
            float q_im = (m_im * are - m_re * aim) * inv;
            float c_r = C_re[h * NS_ + m], c_i = C_im[h * NS_ + m];
            float cdre = c_r * q_re - c_i * q_im;
            float cdim = c_r * q_im + c_i * q_re;
            float el = expf(dre * fl);
            float cl, sl; __sincosf(dim * fl, &sl, &cl);
            val += el * (cdre * cl - cdim * sl);
        }
        val *= 2.0f;
        if (l == 0) val += D[h];
    }

    __shared__ float sc[512];
    sc[l] = (l < T_) ? val : 0.0f;
    __syncthreads();
    for (int off = 1; off < 512; off <<= 1) {
        float add = (l >= off) ? sc[l - off] : 0.0f;
        __syncthreads();
        sc[l] += add;
        __syncthreads();
    }

    if (l < T_) {
        koff[l * H_ + h] = b_in[h] * sc[l];
        unsigned short bv = f32_to_bf16(val);
#pragma unroll
        for (int r = 0; r < 8; r++)
            Krev[((size_t)r * H_ + h) * KW_ + (T_ - 1 - l) + r] = bv;
    }
}

// ---------------------------------------------------------------------------
// K2: per-h Toeplitz conv GEMM.  Block = 128 bn x 128 t, one h; 4 waves in
// 2x2 quadrants of 64x64.  K = tau in 128-chunks (nkb = t0/128+1).
// A = xbf rows, B rows = Krev_h sliding windows (copy r=(-L)&7 -> 16B align).
// Both staged via width-4 global_load_lds into +8-padded LDS rows.
// Epilogue: y = win*acc + koff, gelu(tanh), store bf16 to Y[q][h].
// ---------------------------------------------------------------------------
__global__ __launch_bounds__(256, 2) void k_conv(
        const unsigned short* __restrict__ xbf,    // [1024][TP_]
        const unsigned short* __restrict__ Krev,   // [8][128][KW_]
        const float* __restrict__ koff,            // [354][128]
        const float* __restrict__ W_in,
        unsigned short* __restrict__ Y) {
    __shared__ unsigned short A_lds[128 * 136];    // 34 KB, stride 136 -> 2-way max
    __shared__ unsigned short B_lds[128 * 136];    // 34 KB

    const int tid  = threadIdx.x;
    const int w    = tid >> 6;
    const int lane = tid & 63;
    const int quad = lane >> 4;
    const int l16  = lane & 15;
    const int h    = blockIdx.x;
    const int bn0  = blockIdx.y * 128;
    const int t0   = blockIdx.z * 128;
    const int wm   = (w & 1) * 64;                 // bn quadrant
    const int wn   = (w >> 1) * 64;                // t quadrant
    const int nkb  = (t0 >> 7) + 1;

    f32x4 acc[4][4];
#pragma unroll
    for (int mt = 0; mt < 4; mt++)
#pragma unroll
        for (int nt = 0; nt < 4; nt++) acc[mt][nt] = (f32x4){0.f, 0.f, 0.f, 0.f};

    const unsigned short* krow = Krev + (size_t)h * KW_;   // copy 0 row for h

    for (int kb = 0; kb < nkb; kb++) {
        const int tau0 = kb << 7;
        __syncthreads();
        // stage A: wave w stages bn rows [32w, 32w+32); one row per instr
#pragma unroll 8
        for (int i = 0; i < 32; i++) {
            int r = w * 32 + i;
            gload_lds4(xbf + (size_t)(bn0 + r) * TP_ + tau0 + lane * 2,
                       &A_lds[r * 136]);
        }
        // stage B: Toeplitz rows B[t_sub][tau] = K'h[t-tau] = Krev_h[353-t+tau]
#pragma unroll 8
        for (int i = 0; i < 32; i++) {
            int r = w * 32 + i;
            int L = 353 - (t0 + r) + tau0;
            if (L < 0) L = 0;                      // dead rows (t>353), junk OK
            int cp = (-L) & 7;                     // copy-select -> 16B aligned
            gload_lds4(krow + (size_t)cp * H_ * KW_ + L + cp + lane * 2,
                       &B_lds[r * 136]);
        }
        __syncthreads();

#pragma unroll
        for (int ks = 0; ks < 4; ks++) {
            bf16x8 af[4], bfr[4];
#pragma unroll
            for (int mt = 0; mt < 4; mt++)
                af[mt] = *(const bf16x8*)&A_lds[(wm + mt * 16 + l16) * 136 + ks * 32 + quad * 8];
#pragma unroll
            for (int nt = 0; nt < 4; nt++)
                bfr[nt] = *(const bf16x8*)&B_lds[(wn + nt * 16 + l16) * 136 + ks * 32 + quad * 8];
#pragma unroll
            for (int nt = 0; nt < 4; nt++)
#pragma unroll
                for (int mt = 0; mt < 4; mt++)
                    acc[mt][nt] = __builtin_amdgcn_mfma_f32_16x16x32_bf16(
                        af[mt], bfr[nt], acc[mt][nt], 0, 0, 0);
        }
    }

    const float win = W_in[h];
#pragma unroll
    for (int nt = 0; nt < 4; nt++) {
        int t = t0 + wn + nt * 16 + l16;
        bool ok  = (t < T_);
        float ko = ok ? koff[t * H_ + h] : 0.0f;
#pragma unroll
        for (int mt = 0; mt < 4; mt++)
#pragma unroll
            for (int rr = 0; rr < 4; rr++) {
                float v = fmaf(acc[mt][nt][rr], win, ko);
                // gelu, tanh approximation (JAX default)
                float a  = 0.7978845608028654f * fmaf(0.044715f, v * v * v, v);
                float e  = __expf(2.0f * a);
                float th = 1.0f - 2.0f / (e + 1.0f);
                float g  = 0.5f * v * (1.0f + th);
                if (ok) {
                    int bn = bn0 + wm + mt * 16 + quad * 4 + rr;
                    Y[((size_t)t * BN_ + bn) * H_ + h] = f32_to_bf16(g);
                }
            }
    }
}

// ---------------------------------------------------------------------------
// K3: MFMA GEMM  g = W_out·y (+bias), GLU, pool over t -> node_sum[bn][j].
// W b-frags register-persistent; Y-tile (32bn x 128h) staged per t via
// width-4 global_load_lds into padded LDS. 59 t-chunks for occupancy.
// ---------------------------------------------------------------------------
__global__ __launch_bounds__(256, 2) void k_glu(
        const unsigned short* __restrict__ Ybf,
        const unsigned short* __restrict__ Wbf,
        const float* __restrict__ b_out,
        float* __restrict__ node_sum) {
    __shared__ unsigned short W_lds[128 * 136];    // 34 KB (two-phase reuse)
    __shared__ unsigned short Yt[32 * 136];        // 8.5 KB

    const int tid  = threadIdx.x;
    const int w    = tid >> 6;
    const int lane = tid & 63;
    const int quad = lane >> 4;
    const int l16  = lane & 15;
    const int bn0  = blockIdx.x * 32;
    const int t0   = blockIdx.y * TC_;

    bf16x8 bfrag[4][4];   // [nt][ks]; nt 0,1 = g1 rows, nt 2,3 = g2 rows

    for (int p = 0; p < 2; p++) {
        __syncthreads();
#pragma unroll
        for (int it = 0; it < 16; it++) {
            int c  = it * 256 + tid;
            int r  = c >> 5;
            int k4 = (c & 31) * 4;
            uint2 v = *(const uint2*)(Wbf + (size_t)(p * 128 + r) * 128 + k4);
            *(uint2*)&W_lds[r * 136 + k4] = v;
        }
        __syncthreads();
#pragma unroll
        for (int nt = 0; nt < 2; nt++) {
            int r = 32 * w + 16 * nt + l16;
#pragma unroll
            for (int ks = 0; ks < 4; ks++)
                bfrag[p * 2 + nt][ks] = *(const bf16x8*)&W_lds[r * 136 + ks * 32 + quad * 8];
        }
    }

    float bo1[2], bo2[2];
#pragma unroll
    for (int p = 0; p < 2; p++) {
        bo1[p] = b_out[32 * w + 16 * p + l16];
        bo2[p] = b_out[128 + 32 * w + 16 * p + l16];
    }

    f32x4 zacc[2][2];
#pragma unroll
    for (int mt = 0; mt < 2; mt++)
#pragma unroll
        for (int p = 0; p < 2; p++) zacc[mt][p] = (f32x4){0.f, 0.f, 0.f, 0.f};

    for (int tt = 0; tt < TC_; tt++) {
        int t = t0 + tt;
        if (t >= T_) break;                        // block-uniform
        __syncthreads();
        // stage 32 Y rows (256 B each): wave w stages rows [8w, 8w+8)
#pragma unroll
        for (int i = 0; i < 8; i++) {
            int r = w * 8 + i;
            gload_lds4(Ybf + ((size_t)t * BN_ + bn0 + r) * H_ + lane * 2,
                       &Yt[r * 136]);
        }
        __syncthreads();

        bf16x8 afrag[2][4];
#pragma unroll
        for (int mt = 0; mt < 2; mt++)
#pragma unroll
            for (int ks = 0; ks < 4; ks++)
                afrag[mt][ks] = *(const bf16x8*)&Yt[(mt * 16 + l16) * 136 + ks * 32 + quad * 8];

        f32x4 acc[2][4];
#pragma unroll
        for (int mt = 0; mt < 2; mt++)
#pragma unroll
            for (int nt = 0; nt < 4; nt++) acc[mt][nt] = (f32x4){0.f, 0.f, 0.f, 0.f};

#pragma unroll
        for (int ks = 0; ks < 4; ks++)
#pragma unroll
            for (int nt = 0; nt < 4; nt++)
#pragma unroll
                for (int mt = 0; mt < 2; mt++)
                    acc[mt][nt] = __builtin_amdgcn_mfma_f32_16x16x32_bf16(
                        afrag[mt][ks], bfrag[nt][ks], acc[mt][nt], 0, 0, 0);

#pragma unroll
        for (int mt = 0; mt < 2; mt++)
#pragma unroll
            for (int p = 0; p < 2; p++)
#pragma unroll
                for (int r = 0; r < 4; r++) {
                    float a  = acc[mt][p][r] + bo1[p];
                    float bs = acc[mt][p + 2][r] + bo2[p];
                    float sg = 1.0f / (1.0f + __expf(-bs));
                    zacc[mt][p][r] += a * sg;
                }
    }

#pragma unroll
    for (int mt = 0; mt < 2; mt++)
#pragma unroll
        for (int p = 0; p < 2; p++)
#pragma unroll
            for (int r = 0; r < 4; r++) {
                int bn = bn0 + 16 * mt + quad * 4 + r;
                int j  = 32 * w + 16 * p + l16;
                atomicAdd(&node_sum[bn * H_ + j], zacc[mt][p][r]);
            }
}

// ---------------------------------------------------------------------------
// K4: logits (unchanged)
// ---------------------------------------------------------------------------
__global__ void k_cls(const float* __restrict__ node_sum,
                      const float* __restrict__ W_cls, const float* __restrict__ b_cls,
                      float* __restrict__ out) {
    const int b = blockIdx.x, tid = threadIdx.x;
    float s = 0.0f;
    for (int i = tid; i < N_ * H_; i += 256)
        s += node_sum[b * (N_ * H_) + i] * W_cls[i & (H_ - 1)];
    __shared__ float red[256];
    red[tid] = s;
    __syncthreads();
    for (int off = 128; off > 0; off >>= 1) {
        if (tid < off) red[tid] += red[tid + off];
        __syncthreads();
    }
    if (tid == 0) out[b] = red[0] * (1.0f / (354.0f * 64.0f)) + b_cls[0];
}

// ---------------------------------------------------------------------------
extern "C" void kernel_launch(void* const* d_in, const int* in_sizes, int n_in,
                              void* d_out, int out_size, void* d_ws, size_t ws_size,
                              hipStream_t stream) {
    const float* x      = (const float*)d_in[0];
    const float* W_in   = (const float*)d_in[1];
    const float* b_in   = (const float*)d_in[2];
    const float* log_dt = (const float*)d_in[3];
    const float* A_re   = (const float*)d_in[4];
    const float* A_im   = (const float*)d_in[5];
    const float* C_re   = (const float*)d_in[6];
    const float* C_im   = (const float*)d_in[7];
    const float* D      = (const float*)d_in[8];
    const float* W_out  = (const float*)d_in[9];
    const float* b_out  = (const float*)d_in[10];
    const float* W_cls  = (const float*)d_in[11];
    const float* b_cls  = (const float*)d_in[12];

    char* ws = (char*)d_ws;
    // [node_sum 512K][xbf 768K][Krev 1M] contiguous -> ONE memset; rest written fully
    float*          node_sum = (float*)(ws + 0);                  //   524288 B
    unsigned short* xbf      = (unsigned short*)(ws + 524288);    //   786432 B
    unsigned short* Krev     = (unsigned short*)(ws + 1310720);   //  1048576 B
    float*          koff     = (float*)(ws + 2359296);            //   181248 B
    unsigned short* Wbf      = (unsigned short*)(ws + 2540544);   //    65536 B
    unsigned short* Y        = (unsigned short*)(ws + 2606080);   // 92798976 B

    hipMemsetAsync(ws, 0, 2359296, stream);
    k_prep<<<dim3((T_ * BN_ + 2 * H_ * H_ + 255) / 256), dim3(256), 0, stream>>>(
        x, W_out, xbf, Wbf);
    k_kern<<<dim3(H_), dim3(512), 0, stream>>>(
        log_dt, A_re, A_im, C_re, C_im, b_in, D, Krev, koff);
    k_conv<<<dim3(H_, BN_ / 128, 3), dim3(256), 0, stream>>>(xbf, Krev, koff, W_in, Y);
    k_glu<<<dim3(BN_ / 32, (T_ + TC_ - 1) / TC_), dim3(256), 0, stream>>>(
        Y, Wbf, b_out, node_sum);
    k_cls<<<dim3(B_), dim3(256), 0, stream>>>(node_sum, W_cls, b_cls, (float*)d_out);
}

// Round 5
// 255.140 us; speedup vs baseline: 2.1356x; 2.1356x over previous
//
#include <hip/hip_runtime.h>
#include <hip/hip_bf16.h>

// R5: R4's per-h conv block wrote Y with 256B-stride 2B stores -> 17x HBM
// write amplification (WRITE_SIZE 90MB->1.6GB, 51% HBM peak on garbage).
// Fix + fusion: block = 128bn x 128h at fixed t computes the conv tile AND
// immediately consumes it: gelu -> y-tile in LDS -> 2-phase W_out GEMM ->
// GLU -> t-pool in regs -> atomicAdd node_sum. Y never touches HBM; k_glu
// dispatch eliminated. G=4 consecutive t per block amortizes W staging and
// divides atomics by 4.

#define B_  16
#define T_  354
#define N_  64
#define H_  128
#define NS_ 32
#define BN_ (B_*N_)          // 1024 sequences
#define TP_ 384              // padded tau range for xbf rows
#define KW_ 512              // padded Krev row length
#define G_  4                // t's per fused block
#define NG_ ((T_ + G_ - 1) / G_)   // 89 t-groups

typedef __attribute__((ext_vector_type(8))) short bf16x8;
typedef __attribute__((ext_vector_type(4))) float f32x4;

static __device__ __forceinline__ unsigned short f32_to_bf16(float f) {
    unsigned int u = __float_as_uint(f);
    unsigned int r = 0x7FFFu + ((u >> 16) & 1u);   // RNE
    return (unsigned short)((u + r) >> 16);
}

// async global->LDS, 4 B per lane: one 256 B row per instruction, wave-uniform
// LDS base + lane*4 (padded LDS rows legal at this width).
static __device__ __forceinline__ void gload_lds4(const void* g, void* l) {
    __builtin_amdgcn_global_load_lds(
        (const __attribute__((address_space(1))) unsigned int*)g,
        (__attribute__((address_space(3))) unsigned int*)l, 4, 0, 0);
}

// ---------------------------------------------------------------------------
// K0: fused prep — xbf[bn][tau] bf16 transpose-cast + W_out bf16 cast
// ---------------------------------------------------------------------------
__global__ void k_prep(const float* __restrict__ x, const float* __restrict__ W_out,
                       unsigned short* __restrict__ xbf, unsigned short* __restrict__ Wbf) {
    int id = blockIdx.x * blockDim.x + threadIdx.x;
    if (id < T_ * BN_) {
        int t  = id >> 10;
        int bn = id & 1023;
        float v = x[(bn >> 6) * (T_ * N_) + t * N_ + (bn & 63)];
        xbf[bn * TP_ + t] = f32_to_bf16(v);
    } else {
        int i = id - T_ * BN_;
        if (i < 2 * H_ * H_) Wbf[i] = f32_to_bf16(W_out[i]);
    }
}

// ---------------------------------------------------------------------------
// K1: S4D kernel taps.
//   K'[h,l] = 2*Sum_m Re(Cd[h,m] * exp(dtA*l))  (+ D[h] at l=0)
//   Krev_r[h][(353-l)+r] = bf16(K') for r=0..7  (shift-aligned reversed copies)
//   koff[t][h] = b_in[h] * cumsum_{l<=t} K'[h,l]
// ---------------------------------------------------------------------------
__global__ __launch_bounds__(512) void k_kern(
        const float* __restrict__ log_dt,
        const float* __restrict__ A_re, const float* __restrict__ A_im,
        const float* __restrict__ C_re, const float* __restrict__ C_im,
        const float* __restrict__ b_in, const float* __restrict__ D,
        unsigned short* __restrict__ Krev, float* __restrict__ koff) {
    const int h = blockIdx.x;
    const int l = threadIdx.x;

    float val = 0.0f;
    if (l < T_) {
        float dt = expf(log_dt[h]);
        float fl = (float)l;
#pragma unroll 4
        for (int m = 0; m < NS_; m++) {
            float are = A_re[h * NS_ + m], aim = A_im[h * NS_ + m];
            float dre = are * dt, dim = aim * dt;
            float er  = expf(dre);
            float c1, s1; __sincosf(dim, &s1, &c1);
            float e_re = er * c1, e_im = er * s1;
            float m_re = e_re - 1.0f, m_im = e_im;
            float inv  = 1.0f / (are * are + aim * aim);
            float q_re = (m_re * are + m_im * aim) * inv;
            float q_im = (m_im * are - m_re * aim) * inv;
            float c_r = C_re[h * NS_ + m], c_i = C_im[h * NS_ + m];
            float cdre = c_r * q_re - c_i * q_im;
            float cdim = c_r * q_im + c_i * q_re;
            float el = expf(dre * fl);
            float cl, sl; __sincosf(dim * fl, &sl, &cl);
            val += el * (cdre * cl - cdim * sl);
        }
        val *= 2.0f;
        if (l == 0) val += D[h];
    }

    __shared__ float sc[512];
    sc[l] = (l < T_) ? val : 0.0f;
    __syncthreads();
    for (int off = 1; off < 512; off <<= 1) {
        float add = (l >= off) ? sc[l - off] : 0.0f;
        __syncthreads();
        sc[l] += add;
        __syncthreads();
    }

    if (l < T_) {
        koff[l * H_ + h] = b_in[h] * sc[l];
        unsigned short bv = f32_to_bf16(val);
#pragma unroll
        for (int r = 0; r < 8; r++)
            Krev[((size_t)r * H_ + h) * KW_ + (T_ - 1 - l) + r] = bv;
    }
}

// ---------------------------------------------------------------------------
// K2: fused conv + gelu + W_out GEMM + GLU + t-pool.
// Block = 128 bn x 128 h, G_ consecutive t's; 4 waves in 2x2 quadrants (64x64).
// Per t: Toeplitz conv over tau (nkb = t/128+1 kbs, A/B LDS-staged), gelu ->
// y-tile into A_lds (reuse), W phase p -> B_lds (reuse), GEMM -> acc1/acc2,
// GLU -> zacc (regs). End: atomicAdd zacc into node_sum[bn][j].
// ---------------------------------------------------------------------------
__global__ __launch_bounds__(256, 2) void k_fused(
        const unsigned short* __restrict__ xbf,    // [1024][TP_]
        const unsigned short* __restrict__ Krev,   // [8][128][KW_]
        const float* __restrict__ koff,            // [354][128]
        const float* __restrict__ W_in,
        const unsigned short* __restrict__ Wbf,    // [256][128]
        const float* __restrict__ b_out,
        float* __restrict__ node_sum) {
    __shared__ unsigned short A_lds[128 * 136];    // A tile / y tile (34 KB)
    __shared__ unsigned short B_lds[128 * 136];    // Krev tile / W tile (34 KB)

    const int tid  = threadIdx.x;
    const int w    = tid >> 6;
    const int lane = tid & 63;
    const int quad = lane >> 4;
    const int l16  = lane & 15;
    const int bn0  = blockIdx.x * 128;
    const int tg0  = blockIdx.y * G_;
    const int wm   = (w & 1) * 64;                 // bn quadrant
    const int wn   = (w >> 1) * 64;                // h / j quadrant

    // per-lane constants for the wave's n-columns
    float win[4], bo1[4], bo2[4];
#pragma unroll
    for (int nt = 0; nt < 4; nt++) {
        int c = wn + nt * 16 + l16;
        win[nt] = W_in[c];
        bo1[nt] = b_out[c];
        bo2[nt] = b_out[128 + c];
    }

    f32x4 zacc[4][4];
#pragma unroll
    for (int mt = 0; mt < 4; mt++)
#pragma unroll
        for (int nt = 0; nt < 4; nt++) zacc[mt][nt] = (f32x4){0.f, 0.f, 0.f, 0.f};

    for (int g = 0; g < G_; g++) {
        const int t = tg0 + g;
        if (t >= T_) break;                        // block-uniform
        const int nkb = (t >> 7) + 1;

        // ---- Toeplitz conv: acc[bn][h] = Sum_tau x[bn][tau] * K'_h[t-tau] ----
        f32x4 acc[4][4];
#pragma unroll
        for (int mt = 0; mt < 4; mt++)
#pragma unroll
            for (int nt = 0; nt < 4; nt++) acc[mt][nt] = (f32x4){0.f, 0.f, 0.f, 0.f};

        for (int kb = 0; kb < nkb; kb++) {
            const int tau0 = kb << 7;
            const int L    = 353 - t + tau0;       // >= 0
            const int cp   = (-L) & 7;             // copy-select -> 16B align
            __syncthreads();                       // LDS free of prior readers
#pragma unroll 8
            for (int i = 0; i < 32; i++) {
                int r = w * 32 + i;
                gload_lds4(xbf + (size_t)(bn0 + r) * TP_ + tau0 + lane * 2,
                           &A_lds[r * 136]);
            }
#pragma unroll 8
            for (int i = 0; i < 32; i++) {
                int h = w * 32 + i;
                gload_lds4(Krev + ((size_t)cp * H_ + h) * KW_ + (L + cp) + lane * 2,
                           &B_lds[h * 136]);
            }
            __syncthreads();

#pragma unroll
            for (int ks = 0; ks < 4; ks++) {
                bf16x8 af[4], bfr[4];
#pragma unroll
                for (int mt = 0; mt < 4; mt++)
                    af[mt] = *(const bf16x8*)&A_lds[(wm + mt * 16 + l16) * 136 + ks * 32 + quad * 8];
#pragma unroll
                for (int nt = 0; nt < 4; nt++)
                    bfr[nt] = *(const bf16x8*)&B_lds[(wn + nt * 16 + l16) * 136 + ks * 32 + quad * 8];
#pragma unroll
                for (int nt = 0; nt < 4; nt++)
#pragma unroll
                    for (int mt = 0; mt < 4; mt++)
                        acc[mt][nt] = __builtin_amdgcn_mfma_f32_16x16x32_bf16(
                            af[mt], bfr[nt], acc[mt][nt], 0, 0, 0);
            }
        }

        // ---- epilogue: y = gelu(win*acc + koff)  -> y-tile in A_lds ----
        float ko[4];
#pragma unroll
        for (int nt = 0; nt < 4; nt++) ko[nt] = koff[t * H_ + wn + nt * 16 + l16];

        __syncthreads();                           // conv reads of LDS done
#pragma unroll
        for (int mt = 0; mt < 4; mt++)
#pragma unroll
            for (int nt = 0; nt < 4; nt++)
#pragma unroll
                for (int rr = 0; rr < 4; rr++) {
                    float v = fmaf(acc[mt][nt][rr], win[nt], ko[nt]);
                    float a  = 0.7978845608028654f * fmaf(0.044715f, v * v * v, v);
                    float e  = __expf(2.0f * a);
                    float th = 1.0f - 2.0f / (e + 1.0f);
                    float ge = 0.5f * v * (1.0f + th);
                    A_lds[(wm + mt * 16 + quad * 4 + rr) * 136 + wn + nt * 16 + l16]
                        = f32_to_bf16(ge);
                }

        // ---- GEMM phase 0: j in [0,128) ----
#pragma unroll 8
        for (int i = 0; i < 32; i++) {
            int r = w * 32 + i;
            gload_lds4(Wbf + (size_t)r * H_ + lane * 2, &B_lds[r * 136]);
        }
        __syncthreads();                           // drain ds_writes + gloads

        f32x4 acc1[4][4];
#pragma unroll
        for (int mt = 0; mt < 4; mt++)
#pragma unroll
            for (int nt = 0; nt < 4; nt++) acc1[mt][nt] = (f32x4){0.f, 0.f, 0.f, 0.f};
#pragma unroll
        for (int ks = 0; ks < 4; ks++) {
            bf16x8 af[4], bfr[4];
#pragma unroll
            for (int mt = 0; mt < 4; mt++)
                af[mt] = *(const bf16x8*)&A_lds[(wm + mt * 16 + l16) * 136 + ks * 32 + quad * 8];
#pragma unroll
            for (int nt = 0; nt < 4; nt++)
                bfr[nt] = *(const bf16x8*)&B_lds[(wn + nt * 16 + l16) * 136 + ks * 32 + quad * 8];
#pragma unroll
            for (int nt = 0; nt < 4; nt++)
#pragma unroll
                for (int mt = 0; mt < 4; mt++)
                    acc1[mt][nt] = __builtin_amdgcn_mfma_f32_16x16x32_bf16(
                        af[mt], bfr[nt], acc1[mt][nt], 0, 0, 0);
        }
        __syncthreads();                           // phase-0 reads done

        // ---- GEMM phase 1: j in [128,256) ----
#pragma unroll 8
        for (int i = 0; i < 32; i++) {
            int r = w * 32 + i;
            gload_lds4(Wbf + (size_t)(128 + r) * H_ + lane * 2, &B_lds[r * 136]);
        }
        __syncthreads();

        f32x4 acc2[4][4];
#pragma unroll
        for (int mt = 0; mt < 4; mt++)
#pragma unroll
            for (int nt = 0; nt < 4; nt++) acc2[mt][nt] = (f32x4){0.f, 0.f, 0.f, 0.f};
#pragma unroll
        for (int ks = 0; ks < 4; ks++) {
            bf16x8 af[4], bfr[4];
#pragma unroll
            for (int mt = 0; mt < 4; mt++)
                af[mt] = *(const bf16x8*)&A_lds[(wm + mt * 16 + l16) * 136 + ks * 32 + quad * 8];
#pragma unroll
            for (int nt = 0; nt < 4; nt++)
                bfr[nt] = *(const bf16x8*)&B_lds[(wn + nt * 16 + l16) * 136 + ks * 32 + quad * 8];
#pragma unroll
            for (int nt = 0; nt < 4; nt++)
#pragma unroll
                for (int mt = 0; mt < 4; mt++)
                    acc2[mt][nt] = __builtin_amdgcn_mfma_f32_16x16x32_bf16(
                        af[mt], bfr[nt], acc2[mt][nt], 0, 0, 0);
        }

        // ---- GLU + t-pool (registers) ----
#pragma unroll
        for (int mt = 0; mt < 4; mt++)
#pragma unroll
            for (int nt = 0; nt < 4; nt++)
#pragma unroll
                for (int rr = 0; rr < 4; rr++) {
                    float a  = acc1[mt][nt][rr] + bo1[nt];
                    float bs = acc2[mt][nt][rr] + bo2[nt];
                    float sg = 1.0f / (1.0f + __expf(-bs));
                    zacc[mt][nt][rr] += a * sg;
                }
    }

    // ---- flush pooled z: one atomic per (bn,j) per block ----
#pragma unroll
    for (int mt = 0; mt < 4; mt++)
#pragma unroll
        for (int nt = 0; nt < 4; nt++)
#pragma unroll
            for (int rr = 0; rr < 4; rr++) {
                int bn = bn0 + wm + mt * 16 + quad * 4 + rr;
                int j  = wn + nt * 16 + l16;
                atomicAdd(&node_sum[bn * H_ + j], zacc[mt][nt][rr]);
            }
}

// ---------------------------------------------------------------------------
// K3: logits[b] = (1/(T*N)) * sum_{n,h} node_sum[b*64+n][h] * W_cls[h] + b_cls
// ---------------------------------------------------------------------------
__global__ void k_cls(const float* __restrict__ node_sum,
                      const float* __restrict__ W_cls, const float* __restrict__ b_cls,
                      float* __restrict__ out) {
    const int b = blockIdx.x, tid = threadIdx.x;
    float s = 0.0f;
    for (int i = tid; i < N_ * H_; i += 256)
        s += node_sum[b * (N_ * H_) + i] * W_cls[i & (H_ - 1)];
    __shared__ float red[256];
    red[tid] = s;
    __syncthreads();
    for (int off = 128; off > 0; off >>= 1) {
        if (tid < off) red[tid] += red[tid + off];
        __syncthreads();
    }
    if (tid == 0) out[b] = red[0] * (1.0f / (354.0f * 64.0f)) + b_cls[0];
}

// ---------------------------------------------------------------------------
extern "C" void kernel_launch(void* const* d_in, const int* in_sizes, int n_in,
                              void* d_out, int out_size, void* d_ws, size_t ws_size,
                              hipStream_t stream) {
    const float* x      = (const float*)d_in[0];
    const float* W_in   = (const float*)d_in[1];
    const float* b_in   = (const float*)d_in[2];
    const float* log_dt = (const float*)d_in[3];
    const float* A_re   = (const float*)d_in[4];
    const float* A_im   = (const float*)d_in[5];
    const float* C_re   = (const float*)d_in[6];
    const float* C_im   = (const float*)d_in[7];
    const float* D      = (const float*)d_in[8];
    const float* W_out  = (const float*)d_in[9];
    const float* b_out  = (const float*)d_in[10];
    const float* W_cls  = (const float*)d_in[11];
    const float* b_cls  = (const float*)d_in[12];

    char* ws = (char*)d_ws;
    // [node_sum 512K][xbf 768K][Krev 1M] contiguous -> ONE memset
    float*          node_sum = (float*)(ws + 0);                  //   524288 B
    unsigned short* xbf      = (unsigned short*)(ws + 524288);    //   786432 B
    unsigned short* Krev     = (unsigned short*)(ws + 1310720);   //  1048576 B
    float*          koff     = (float*)(ws + 2359296);            //   181248 B
    unsigned short* Wbf      = (unsigned short*)(ws + 2540544);   //    65536 B

    hipMemsetAsync(ws, 0, 2359296, stream);
    k_prep<<<dim3((T_ * BN_ + 2 * H_ * H_ + 255) / 256), dim3(256), 0, stream>>>(
        x, W_out, xbf, Wbf);
    k_kern<<<dim3(H_), dim3(512), 0, stream>>>(
        log_dt, A_re, A_im, C_re, C_im, b_in, D, Krev, koff);
    k_fused<<<dim3(BN_ / 128, NG_), dim3(256), 0, stream>>>(
        xbf, Krev, koff, W_in, Wbf, b_out, node_sum);
    k_cls<<<dim3(B_), dim3(256), 0, stream>>>(node_sum, W_cls, b_cls, (float*)d_out);
}